// Round 16
// baseline (417.797 us; speedup 1.0000x reference)
//
#include <hip/hip_runtime.h>
#include <hip/hip_bf16.h>
#include <math.h>

typedef unsigned int u32;
typedef unsigned short u16;
typedef unsigned long long u64;
typedef __hip_bfloat16 bf16_t;
typedef float f32x4 __attribute__((ext_vector_type(4)));
typedef short bf16x8 __attribute__((ext_vector_type(8)));

__device__ __forceinline__ float blo(u32 p){ union{u32 u; float f;} c; c.u = p << 16; return c.f; }
__device__ __forceinline__ float bhi(u32 p){ union{u32 u; float f;} c; c.u = p & 0xFFFF0000u; return c.f; }
// Raw-HW gates: v_exp_f32 (=2^x) + v_rcp_f32 -- no IEEE divide sequences.
#define LOG2E  1.44269504088896340736f
#define LOG2E2 2.88539008177792681472f
__device__ __forceinline__ float fsigm(float x){
  return __builtin_amdgcn_rcpf(1.0f + __builtin_amdgcn_exp2f(-x*LOG2E));
}
__device__ __forceinline__ float ftanh(float x){
  return 1.0f - 2.0f*__builtin_amdgcn_rcpf(1.0f + __builtin_amdgcn_exp2f(x*LOG2E2));
}
// f32 -> bf16 bits, round-to-nearest-even
__device__ __forceinline__ u16 f2bu(float f){
  union{float f; u32 u;} c; c.f = f;
  u32 u = c.u + 0x7FFFu + ((c.u >> 16) & 1u);
  return (u16)(u >> 16);
}
// __syncthreads minus the vmcnt drain: LDS-writes-visible barrier.
__device__ __forceinline__ void barrier_lds(){
  asm volatile("s_waitcnt lgkmcnt(0)" ::: "memory");
  __builtin_amdgcn_s_barrier();
}

// ws byte offsets
#define WE_OFF   0u
#define L0O_OFF  2129920u
#define SFIN_OFF 6324224u
#define XW_OFF   6455296u     // 32MB xw [8192][1024] f32; embB overlays start
#define WB_OFF   40009728u
// bf16 weight segment element offsets inside wB
#define SEG_WWIH  0
#define SEG_WWHH  131072
#define SEG_FW1   196608
#define SEG_FW2   212992
#define SEG_SWIH0 229376
#define SEG_SWIH1 360448
#define SEG_SWHH  622592
#define SEG_TOTAL 884736
#define EMB_TOTAL 16512      // 129*128 bf16 emb (overlay at XW_OFF)

// =====================================================================
// Kernel 0: one-time f32 -> bf16 weight + embedding conversion into ws.
// =====================================================================
__global__ __launch_bounds__(256) void prep_weights(
    const float* __restrict__ wWih, const float* __restrict__ wWhh,
    const float* __restrict__ fW1,  const float* __restrict__ fW2,
    const float* __restrict__ sWih0,const float* __restrict__ sWih1,
    const float* __restrict__ sWhh, const float* __restrict__ emb,
    u16* __restrict__ dst, u16* __restrict__ embB)
{
  for (int i = blockIdx.x*256 + threadIdx.x; i < SEG_TOTAL + EMB_TOTAL; i += gridDim.x*256){
    if (i < SEG_TOTAL){
      const float* s; int off;
      if      (i < SEG_WWHH ){ s = wWih;  off = i; }
      else if (i < SEG_FW1  ){ s = wWhh;  off = i - SEG_WWHH; }
      else if (i < SEG_FW2  ){ s = fW1;   off = i - SEG_FW1; }
      else if (i < SEG_SWIH0){ s = fW2;   off = i - SEG_FW2; }
      else if (i < SEG_SWIH1){ s = sWih0; off = i - SEG_SWIH0; }
      else if (i < SEG_SWHH ){ s = sWih1; off = i - SEG_SWIH1; }
      else                   { s = sWhh;  off = i - SEG_SWHH; }
      dst[i] = f2bu(s[off]);
    } else {
      embB[i - SEG_TOTAL] = f2bu(emb[i - SEG_TOTAL]);
    }
  }
}

// =====================================================================
// Kernel 1 (MFMA): char-level word embedder. 16 words/block, 512 thr.
// NEW: layer-1 SQ A-fragments prefetched one step ahead (SQ read-only
// during layer 1) -- removes post-barrier ds_read latency from chain.
// Unified xfn prefetch path for both layers.
// =====================================================================
__global__ __launch_bounds__(512, 2) void word_mfma(
    const int* __restrict__ sentences, const int* __restrict__ words,
    const u16* __restrict__ embB,
    const u16* __restrict__ wWihB, const u16* __restrict__ wWhhB,
    const float* __restrict__ wb,
    const u16* __restrict__ fW1B, const float* __restrict__ fb1,
    const u16* __restrict__ fW2B, const float* __restrict__ fb2,
    bf16_t* __restrict__ we_out /* [8320][128] bf16 */)
{
  const int blk  = blockIdx.x;        // 520 blocks x 16 words
  const int tid  = threadIdx.x;
  const int lane = tid & 63;
  const int wv   = tid >> 6;          // wave 0..7
  const int dq   = wv >> 2;           // direction handled by this wave
  const int wq   = wv & 3;            // gate-tile quarter within dir
  const int lr   = lane & 15;
  const int lg   = lane >> 4;

  __shared__ __align__(16) u16 SQ[16*16*128];    // 64KB layer0 out [w][t][c^(w&15)][8]
  __shared__ __align__(16) u16 Hb[2][2][16*64];  // 8KB  h dbuf per dir
  __shared__ __align__(16) u16 HF[16*128];       // 4KB  final hiddens
  __shared__ int chs[256];
  __shared__ int emptyf[16];
  u16* A1 = (u16*)Hb;                            // alias: MLP phase only

  const int wbase = blk*16;
  if (tid < 256){
    int w = tid >> 4, t = tid & 15;
    int gw = wbase + w;
    chs[tid] = (gw < 8192) ? sentences[gw*16 + t] : words[(gw - 8192)*16 + t];
  }
  __syncthreads();
  if (tid < 16){
    int acc = 0;
    #pragma unroll
    for (int i = 0; i < 16; ++i) acc |= chs[tid*16 + i];
    emptyf[tid] = (wbase + tid < 8192) && (acc == 0);
  }
  __syncthreads();

  // whole-block skip: all 16 words are empty sentence slots
  {
    int allz = 1;
    #pragma unroll
    for (int i = 0; i < 16; ++i) allz &= emptyf[i];
    if (allz){
      u64* wo = (u64*)(we_out + (size_t)wbase*128);
      wo[tid] = 0ull;
      return;
    }
  }

  for (int layer = 0; layer < 2; ++layer){
    const int ld = layer*2 + dq;
    bf16x8 bih[4][4], bhh[4][2];
    float bias[4];
    #pragma unroll
    for (int j = 0; j < 4; ++j){
      const int col = (wq + 4*j)*16 + lr;
      bias[j] = wb[ld*256 + col];
      const u16* pih = wWihB + (size_t)(ld*256 + col)*128 + lg*8;
      #pragma unroll
      for (int kk = 0; kk < 4; ++kk) bih[j][kk] = *(const bf16x8*)(pih + kk*32);
      const u16* phh = wWhhB + (size_t)(ld*256 + col)*64 + lg*8;
      #pragma unroll
      for (int kk = 0; kk < 2; ++kk) bhh[j][kk] = *(const bf16x8*)(phh + kk*32);
    }
    float cst[4] = {0.f, 0.f, 0.f, 0.f};
    for (int i = tid; i < 2*2*16*64; i += 512) ((u16*)Hb)[i] = 0;
    __syncthreads();   // Hb zeros + (layer1:) all SQ writes visible
    int cur = 0;
    // prefetch first step's A-fragments (layer0: global emb; layer1: LDS SQ)
    bf16x8 xfn[4];
    {
      const int t0 = dq ? 15 : 0;
      if (layer == 0){
        const u16* xp = embB + (size_t)chs[lr*16 + t0]*128 + lg*8;
        #pragma unroll
        for (int kk = 0; kk < 4; ++kk) xfn[kk] = *(const bf16x8*)(xp + kk*32);
      } else {
        #pragma unroll
        for (int kk = 0; kk < 4; ++kk){
          const int c = (kk*4 + lg) ^ lr;
          xfn[kk] = *(const bf16x8*)&SQ[((lr*16 + t0)*16 + c)*8];
        }
      }
    }
    for (int step = 0; step < 16; ++step){
      const int t = dq ? (15 - step) : step;
      f32x4 ac[4];
      #pragma unroll
      for (int j = 0; j < 4; ++j) ac[j] = (f32x4){bias[j], bias[j], bias[j], bias[j]};
      bf16x8 xf[4];
      #pragma unroll
      for (int kk = 0; kk < 4; ++kk) xf[kk] = xfn[kk];
      if (step < 15){
        const int tn = dq ? (14 - step) : (step + 1);
        if (layer == 0){
          const u16* xp = embB + (size_t)chs[lr*16 + tn]*128 + lg*8;
          #pragma unroll
          for (int kk = 0; kk < 4; ++kk) xfn[kk] = *(const bf16x8*)(xp + kk*32);
        } else {
          #pragma unroll
          for (int kk = 0; kk < 4; ++kk){
            const int c = (kk*4 + lg) ^ lr;
            xfn[kk] = *(const bf16x8*)&SQ[((lr*16 + tn)*16 + c)*8];
          }
        }
      }
      // ih: A = X_t[16 words, 128]
      #pragma unroll
      for (int kk = 0; kk < 4; ++kk){
        #pragma unroll
        for (int j = 0; j < 4; ++j)
          ac[j] = __builtin_amdgcn_mfma_f32_16x16x32_bf16(xf[kk], bih[j][kk], ac[j], 0, 0, 0);
      }
      // hh: A = H[16,64]
      #pragma unroll
      for (int kk = 0; kk < 2; ++kk){
        const int c = (kk*4 + lg) ^ (lr & 7);
        bf16x8 a = *(const bf16x8*)&Hb[dq][cur][(lr*8 + c)*8];
        #pragma unroll
        for (int j = 0; j < 4; ++j)
          ac[j] = __builtin_amdgcn_mfma_f32_16x16x32_bf16(a, bhh[j][kk], ac[j], 0, 0, 0);
      }
      const int u = wq*16 + lr;            // unit 0..63 within dir
      #pragma unroll
      for (int r = 0; r < 4; ++r){
        const int w = lg*4 + r;
        float ig = fsigm(ac[0][r]);
        float fg = fsigm(ac[1][r]);
        float gg = ftanh(ac[2][r]);
        float og = fsigm(ac[3][r]);
        cst[r] = fg*cst[r] + ig*gg;
        float hn = og * ftanh(cst[r]);
        u16 hb = f2bu(hn);
        Hb[dq][cur^1][(w*8 + ((u >> 3) ^ (w & 7)))*8 + (u & 7)] = hb;
        const int d = dq*64 + u;
        const int dc = (d >> 3) ^ (w & 15);
        if (layer == 0)       SQ[((w*16 + t)*16 + dc)*8 + (d & 7)] = hb;
        else if (step == 15)  HF[(w*16 + dc)*8 + (d & 7)] = hb;
      }
      barrier_lds();            // LDS-visible barrier; vmem stays in flight
      cur ^= 1;
    }
  }

  // MLP GEMM1
  {
    const int col = wv*16 + lr;
    float bs = fb1[col];
    bf16x8 b1[4];
    const u16* src = fW1B + (size_t)col*128 + lg*8;
    #pragma unroll
    for (int kk = 0; kk < 4; ++kk) b1[kk] = *(const bf16x8*)(src + kk*32);
    f32x4 ac = (f32x4){bs, bs, bs, bs};
    #pragma unroll
    for (int kk = 0; kk < 4; ++kk){
      const int c = (kk*4 + lg) ^ lr;
      bf16x8 a = *(const bf16x8*)&HF[(lr*16 + c)*8];
      ac = __builtin_amdgcn_mfma_f32_16x16x32_bf16(a, b1[kk], ac, 0, 0, 0);
    }
    __syncthreads();
    #pragma unroll
    for (int r = 0; r < 4; ++r){
      const int w = lg*4 + r;
      A1[(w*16 + ((col >> 3) ^ (w & 15)))*8 + (col & 7)] = f2bu(fmaxf(ac[r], 0.f));
    }
  }
  __syncthreads();
  // MLP GEMM2 (masked for empty sentence slots)
  {
    const int col = wv*16 + lr;
    float bs = fb2[col];
    bf16x8 b2[4];
    const u16* src = fW2B + (size_t)col*128 + lg*8;
    #pragma unroll
    for (int kk = 0; kk < 4; ++kk) b2[kk] = *(const bf16x8*)(src + kk*32);
    f32x4 ac = (f32x4){bs, bs, bs, bs};
    #pragma unroll
    for (int kk = 0; kk < 4; ++kk){
      const int c = (kk*4 + lg) ^ lr;
      bf16x8 a = *(const bf16x8*)&A1[(lr*16 + c)*8];
      ac = __builtin_amdgcn_mfma_f32_16x16x32_bf16(a, b2[kk], ac, 0, 0, 0);
    }
    u16* wo = (u16*)we_out;
    #pragma unroll
    for (int r = 0; r < 4; ++r){
      const int w = lg*4 + r;
      wo[(size_t)(wbase + w)*128 + col] = emptyf[w] ? (u16)0 : f2bu(ac[r]);
    }
  }
}

// =====================================================================
// Kernel 2 (MFMA GEMM): xw[row][1024] = X[row][K] @ W[1024][K]^T + b.
// =====================================================================
template<int KK>
__global__ __launch_bounds__(256, 1) void xw_gemm(
    const u16* __restrict__ X, const u16* __restrict__ W,
    const float* __restrict__ bias, float* __restrict__ out)
{
  const int rowb = blockIdx.x;
  const int colb = blockIdx.y;
  const int tid = threadIdx.x;
  const int lane = tid & 63, wv = tid >> 6;
  const int lr = lane & 15, lg = lane >> 4;
  const int K = KK*32;

  bf16x8 bf[4][KK];
  f32x4 ac[4];
  #pragma unroll
  for (int j = 0; j < 4; ++j){
    const int g = colb*256 + (wv*4 + j)*16 + lr;
    const float bs = bias[g];
    ac[j] = (f32x4){bs, bs, bs, bs};
    const u16* src = W + (size_t)g*K + lg*8;
    #pragma unroll
    for (int kk = 0; kk < KK; ++kk) bf[j][kk] = *(const bf16x8*)(src + kk*32);
  }
  const u16* xr = X + (size_t)(rowb*16 + lr)*K + lg*8;
  #pragma unroll
  for (int kk = 0; kk < KK; ++kk){
    bf16x8 a = *(const bf16x8*)(xr + kk*32);
    #pragma unroll
    for (int j = 0; j < 4; ++j)
      ac[j] = __builtin_amdgcn_mfma_f32_16x16x32_bf16(a, bf[j][kk], ac[j], 0, 0, 0);
  }
  #pragma unroll
  for (int j = 0; j < 4; ++j){
    const int g = colb*256 + (wv*4 + j)*16 + lr;
    #pragma unroll
    for (int r = 0; r < 4; ++r)
      out[(size_t)(rowb*16 + lg*4 + r)*1024 + g] = ac[j][r];
  }
}

// =====================================================================
// Kernel 3 (MFMA): sentence recurrence (r10 body: depth-1 prefetch),
// lgkm-only barrier.
// =====================================================================
__global__ __launch_bounds__(512, 1) void sent_rec(
    const float* __restrict__ xw /* [8192][1024] */,
    const u16* __restrict__ sWhhB /* [4*512][128] */,
    bf16_t* __restrict__ l0out /* layer0: [8192][256] */,
    float* __restrict__ sfin /* layer1: [128][256] */,
    const int layer)
{
  const int dir = blockIdx.x & 1;
  const int sg0 = (blockIdx.x >> 1) << 4;
  const int tid = threadIdx.x;
  const int lane = tid & 63, wv = tid >> 6;
  const int lr = lane & 15, lg = lane >> 4;

  __shared__ __align__(16) u16 Hs[2][2048];

  bf16x8 bhh[4][4];
  #pragma unroll
  for (int j = 0; j < 4; ++j){
    const int g = (wv + 8*j)*16 + lr;
    const u16* p = sWhhB + (size_t)((layer*2 + dir)*512 + g)*128 + lg*8;
    #pragma unroll
    for (int kk = 0; kk < 4; ++kk) bhh[j][kk] = *(const bf16x8*)(p + kk*32);
  }
  for (int i = tid; i < 4096; i += 512) ((u16*)Hs)[i] = 0;
  float cst[4] = {0.f, 0.f, 0.f, 0.f};

  size_t rowoff[4];
  #pragma unroll
  for (int r = 0; r < 4; ++r)
    rowoff[r] = (size_t)(sg0 + lg*4 + r)*64*1024 + dir*512 + wv*16 + lr;

  float xwv[16], xwn[16];
  {
    const int t0 = dir ? 63 : 0;
    #pragma unroll
    for (int j = 0; j < 4; ++j)
      #pragma unroll
      for (int r = 0; r < 4; ++r)
        xwv[j*4 + r] = xw[rowoff[r] + (size_t)t0*1024 + j*128];
  }
  __syncthreads();

  u16* lob = (u16*)l0out;
  int cur = 0;
  for (int step = 0; step < 64; ++step){
    const int t = dir ? (63 - step) : step;
    f32x4 ac[4];
    #pragma unroll
    for (int j = 0; j < 4; ++j)
      ac[j] = (f32x4){xwv[j*4+0], xwv[j*4+1], xwv[j*4+2], xwv[j*4+3]};
    if (step < 63){
      const int tn = dir ? (62 - step) : (step + 1);
      #pragma unroll
      for (int j = 0; j < 4; ++j)
        #pragma unroll
        for (int r = 0; r < 4; ++r)
          xwn[j*4 + r] = xw[rowoff[r] + (size_t)tn*1024 + j*128];
    }
    #pragma unroll
    for (int kk = 0; kk < 4; ++kk){
      const bf16x8 ha = *(const bf16x8*)&Hs[cur][(lr*16 + ((kk*4 + lg) ^ lr))*8];
      #pragma unroll
      for (int j = 0; j < 4; ++j)
        ac[j] = __builtin_amdgcn_mfma_f32_16x16x32_bf16(ha, bhh[j][kk], ac[j], 0, 0, 0);
    }
    const int u = wv*16 + lr;
    #pragma unroll
    for (int r = 0; r < 4; ++r){
      const int s = lg*4 + r;
      float ig = fsigm(ac[0][r]);
      float fg = fsigm(ac[1][r]);
      float gg = ftanh(ac[2][r]);
      float og = fsigm(ac[3][r]);
      cst[r] = fg*cst[r] + ig*gg;
      float hn = og * ftanh(cst[r]);
      Hs[cur^1][(s*16 + ((u >> 3) ^ s))*8 + (u & 7)] = f2bu(hn);
      if (layer == 0)
        lob[((size_t)(sg0 + s)*64 + t)*256 + dir*128 + u] = f2bu(hn);
      else if (step == 63)
        sfin[(size_t)(sg0 + s)*256 + dir*128 + u] = hn;
    }
    barrier_lds();
    cur ^= 1;
    #pragma unroll
    for (int i = 0; i < 16; ++i) xwv[i] = xwn[i];
  }
}

// =====================================================================
// Kernel 4: head (unchanged). Output f32 [128][2].
// =====================================================================
__global__ __launch_bounds__(256) void head_kernel(
    const float* __restrict__ sfin, const bf16_t* __restrict__ wet,
    const float* __restrict__ sW1, const float* __restrict__ sb1,
    const float* __restrict__ sW2, const float* __restrict__ sb2,
    const float* __restrict__ cW0, const float* __restrict__ cb0,
    const float* __restrict__ cW1, const float* __restrict__ cb1,
    const float* __restrict__ cW2, const float* __restrict__ cb2,
    float* __restrict__ out)
{
  const int bs = blockIdx.x, tid = threadIdx.x;
  __shared__ __align__(16) float hin[256];
  __shared__ __align__(16) float a1[256];
  __shared__ __align__(16) float xcat[384];
  __shared__ __align__(16) float b0o[256];
  __shared__ __align__(16) float h1o[128];
  __shared__ float lg[2];

  hin[tid] = sfin[(size_t)bs*256 + tid];
  if (tid < 64){
    const u32* src = (const u32*)(wet + (size_t)bs*128);
    u32 p = src[tid];
    xcat[256 + tid*2]     = blo(p);
    xcat[256 + tid*2 + 1] = bhi(p);
  }
  __syncthreads();
  {
    const float4* wr = (const float4*)(sW1 + (size_t)tid*256);
    float acc = sb1[tid];
    #pragma unroll
    for (int i = 0; i < 64; ++i){
      float4 v = wr[i]; const float* hp = &hin[i*4];
      acc += hp[0]*v.x + hp[1]*v.y + hp[2]*v.z + hp[3]*v.w;
    }
    a1[tid] = fmaxf(acc, 0.0f);
  }
  __syncthreads();
  {
    const float4* wr = (const float4*)(sW2 + (size_t)tid*256);
    float acc = sb2[tid];
    #pragma unroll
    for (int i = 0; i < 64; ++i){
      float4 v = wr[i]; const float* hp = &a1[i*4];
      acc += hp[0]*v.x + hp[1]*v.y + hp[2]*v.z + hp[3]*v.w;
    }
    xcat[tid] = acc;
  }
  __syncthreads();
  {
    const float4* wr = (const float4*)(cW0 + (size_t)tid*384);
    float acc = cb0[tid];
    #pragma unroll
    for (int i = 0; i < 96; ++i){
      float4 v = wr[i]; const float* hp = &xcat[i*4];
      acc += hp[0]*v.x + hp[1]*v.y + hp[2]*v.z + hp[3]*v.w;
    }
    b0o[tid] = fmaxf(acc, 0.0f);
  }
  __syncthreads();
  if (tid < 128){
    const float4* wr = (const float4*)(cW1 + (size_t)tid*256);
    float acc = cb1[tid];
    #pragma unroll
    for (int i = 0; i < 64; ++i){
      float4 v = wr[i]; const float* hp = &b0o[i*4];
      acc += hp[0]*v.x + hp[1]*v.y + hp[2]*v.z + hp[3]*v.w;
    }
    h1o[tid] = fmaxf(acc, 0.0f);
  }
  __syncthreads();
  if (tid < 2){
    const float4* wr = (const float4*)(cW2 + (size_t)tid*128);
    float acc = cb2[tid];
    #pragma unroll
    for (int i = 0; i < 32; ++i){
      float4 v = wr[i]; const float* hp = &h1o[i*4];
      acc += hp[0]*v.x + hp[1]*v.y + hp[2]*v.z + hp[3]*v.w;
    }
    lg[tid] = acc;
  }
  __syncthreads();
  if (tid == 0){
    float m = fmaxf(lg[0], lg[1]);
    float lse = m + logf(expf(lg[0] - m) + expf(lg[1] - m));
    out[bs*2 + 0] = lg[0] - lse;
    out[bs*2 + 1] = lg[1] - lse;
  }
}

extern "C" void kernel_launch(void* const* d_in, const int* in_sizes, int n_in,
                              void* d_out, int out_size, void* d_ws, size_t ws_size,
                              hipStream_t stream) {
  const int*   sentences = (const int*)d_in[0];
  const int*   words     = (const int*)d_in[1];
  const float* emb    = (const float*)d_in[2];
  const float* wWih   = (const float*)d_in[3];
  const float* wWhh   = (const float*)d_in[4];
  const float* wb     = (const float*)d_in[5];
  const float* fW1    = (const float*)d_in[6];
  const float* fb1    = (const float*)d_in[7];
  const float* fW2    = (const float*)d_in[8];
  const float* fb2    = (const float*)d_in[9];
  const float* sWih0  = (const float*)d_in[10];
  const float* sWih1  = (const float*)d_in[11];
  const float* sWhh   = (const float*)d_in[12];
  const float* sb     = (const float*)d_in[13];
  const float* sW1    = (const float*)d_in[14];
  const float* sb1    = (const float*)d_in[15];
  const float* sW2    = (const float*)d_in[16];
  const float* sb2    = (const float*)d_in[17];
  const float* cW0    = (const float*)d_in[18];
  const float* cb0    = (const float*)d_in[19];
  const float* cW1    = (const float*)d_in[20];
  const float* cb1    = (const float*)d_in[21];
  const float* cW2    = (const float*)d_in[22];
  const float* cb2    = (const float*)d_in[23];

  char* W = (char*)d_ws;
  bf16_t* we   = (bf16_t*)(W + WE_OFF);     // [8320][128] bf16
  bf16_t* l0o  = (bf16_t*)(W + L0O_OFF);    // [8192][256] bf16
  float*  sfin = (float*) (W + SFIN_OFF);   // [128][256] f32
  float*  xw   = (float*) (W + XW_OFF);     // [8192][1024] f32
  u16*    embB = (u16*)   (W + XW_OFF);     // bf16 emb overlay (freed before xw writes)
  u16*    wB   = (u16*)   (W + WB_OFF);     // bf16 weights
  bf16_t* wet  = we + (size_t)8192*128;

  prep_weights<<<dim3(440), dim3(256), 0, stream>>>(
      wWih, wWhh, fW1, fW2, sWih0, sWih1, sWhh, emb, wB, embB);
  word_mfma<<<dim3(520), dim3(512), 0, stream>>>(
      sentences, words, embB,
      wB + SEG_WWIH, wB + SEG_WWHH, wb,
      wB + SEG_FW1, fb1, wB + SEG_FW2, fb2, we);
  xw_gemm<4><<<dim3(512, 4), dim3(256), 0, stream>>>(
      (const u16*)we, wB + SEG_SWIH0, sb, xw);
  sent_rec<<<dim3(16), dim3(512), 0, stream>>>(xw, wB + SEG_SWHH, l0o, sfin, 0);
  xw_gemm<8><<<dim3(512, 4), dim3(256), 0, stream>>>(
      (const u16*)l0o, wB + SEG_SWIH1, sb + 1024, xw);
  sent_rec<<<dim3(16), dim3(512), 0, stream>>>(xw, wB + SEG_SWHH, l0o, sfin, 1);
  head_kernel<<<dim3(128), dim3(256), 0, stream>>>(
      sfin, wet, sW1, sb1, sW2, sb2, cW0, cb0, cW1, cb1, cW2, cb2,
      (float*)d_out);
}

// Round 17
// 381.959 us; speedup vs baseline: 1.0938x; 1.0938x over previous
//
#include <hip/hip_runtime.h>
#include <hip/hip_bf16.h>
#include <math.h>

typedef unsigned int u32;
typedef unsigned short u16;
typedef __hip_bfloat16 bf16_t;
typedef float f32x4 __attribute__((ext_vector_type(4)));
typedef short bf16x8 __attribute__((ext_vector_type(8)));

__device__ __forceinline__ float blo(u32 p){ union{u32 u; float f;} c; c.u = p << 16; return c.f; }
__device__ __forceinline__ float bhi(u32 p){ union{u32 u; float f;} c; c.u = p & 0xFFFF0000u; return c.f; }
// Raw-HW gates: v_exp_f32 (=2^x) + v_rcp_f32 -- no IEEE divide sequences.
#define LOG2E  1.44269504088896340736f
#define LOG2E2 2.88539008177792681472f
__device__ __forceinline__ float fsigm(float x){
  return __builtin_amdgcn_rcpf(1.0f + __builtin_amdgcn_exp2f(-x*LOG2E));
}
__device__ __forceinline__ float ftanh(float x){
  return 1.0f - 2.0f*__builtin_amdgcn_rcpf(1.0f + __builtin_amdgcn_exp2f(x*LOG2E2));
}
// f32 -> bf16 bits, round-to-nearest-even
__device__ __forceinline__ u16 f2bu(float f){
  union{float f; u32 u;} c; c.f = f;
  u32 u = c.u + 0x7FFFu + ((c.u >> 16) & 1u);
  return (u16)(u >> 16);
}

// ws byte offsets
#define WE_OFF   0u
#define L0O_OFF  2129920u
#define SFIN_OFF 6324224u
#define XW_OFF   6455296u
#define WB_OFF   40009728u
// bf16 weight segment element offsets inside wB
#define SEG_WWIH  0
#define SEG_WWHH  131072
#define SEG_FW1   196608
#define SEG_FW2   212992
#define SEG_SWIH0 229376
#define SEG_SWIH1 360448
#define SEG_SWHH  622592
#define SEG_TOTAL 884736
#define EMB_TOTAL 16512      // 129*128 bf16 emb, stored at XW_OFF (freed before xw_gemm)

// =====================================================================
// Kernel 0: one-time f32 -> bf16 weight + embedding conversion into ws.
// =====================================================================
__global__ __launch_bounds__(256) void prep_weights(
    const float* __restrict__ wWih, const float* __restrict__ wWhh,
    const float* __restrict__ fW1,  const float* __restrict__ fW2,
    const float* __restrict__ sWih0,const float* __restrict__ sWih1,
    const float* __restrict__ sWhh, const float* __restrict__ emb,
    u16* __restrict__ dst, u16* __restrict__ embB)
{
  for (int i = blockIdx.x*256 + threadIdx.x; i < SEG_TOTAL + EMB_TOTAL; i += gridDim.x*256){
    if (i < SEG_TOTAL){
      const float* s; int off;
      if      (i < SEG_WWHH ){ s = wWih;  off = i; }
      else if (i < SEG_FW1  ){ s = wWhh;  off = i - SEG_WWHH; }
      else if (i < SEG_FW2  ){ s = fW1;   off = i - SEG_FW1; }
      else if (i < SEG_SWIH0){ s = fW2;   off = i - SEG_FW2; }
      else if (i < SEG_SWIH1){ s = sWih0; off = i - SEG_SWIH0; }
      else if (i < SEG_SWHH ){ s = sWih1; off = i - SEG_SWIH1; }
      else                   { s = sWhh;  off = i - SEG_SWHH; }
      dst[i] = f2bu(s[off]);
    } else {
      embB[i - SEG_TOTAL] = f2bu(emb[i - SEG_TOTAL]);
    }
  }
}

// =====================================================================
// Kernel 1 (MFMA): char-level word embedder. 16 words per block,
// 512 threads (8 waves): waves 0-3 = dir0, waves 4-7 = dir1.
// Layer-0 A-frags straight from global bf16 emb, prefetched 1 step ahead.
// (round-10 configuration: best measured)
// =====================================================================
__global__ __launch_bounds__(512, 2) void word_mfma(
    const int* __restrict__ sentences, const int* __restrict__ words,
    const u16* __restrict__ embB,
    const u16* __restrict__ wWihB, const u16* __restrict__ wWhhB,
    const float* __restrict__ wb,
    const u16* __restrict__ fW1B, const float* __restrict__ fb1,
    const u16* __restrict__ fW2B, const float* __restrict__ fb2,
    bf16_t* __restrict__ we_out /* [8320][128] bf16 */)
{
  const int blk  = blockIdx.x;        // 520 blocks x 16 words
  const int tid  = threadIdx.x;
  const int lane = tid & 63;
  const int wv   = tid >> 6;          // wave 0..7
  const int dq   = wv >> 2;           // direction handled by this wave
  const int wq   = wv & 3;            // gate-tile quarter within dir
  const int lr   = lane & 15;
  const int lg   = lane >> 4;

  __shared__ __align__(16) u16 SQ[16*16*128];    // 64KB layer0 out [w][t][c^(w&15)][8]
  __shared__ __align__(16) u16 Hb[2][2][16*64];  // 8KB  h dbuf per dir
  __shared__ __align__(16) u16 HF[16*128];       // 4KB  final hiddens
  __shared__ int chs[256];
  __shared__ int emptyf[16];
  u16* A1 = (u16*)Hb;                            // alias: MLP phase only

  const int wbase = blk*16;
  if (tid < 256){
    int w = tid >> 4, t = tid & 15;
    int gw = wbase + w;
    chs[tid] = (gw < 8192) ? sentences[gw*16 + t] : words[(gw - 8192)*16 + t];
  }
  __syncthreads();
  if (tid < 16){
    int acc = 0;
    #pragma unroll
    for (int i = 0; i < 16; ++i) acc |= chs[tid*16 + i];
    emptyf[tid] = (wbase + tid < 8192) && (acc == 0);
  }
  __syncthreads();

  for (int layer = 0; layer < 2; ++layer){
    const int ld = layer*2 + dq;
    bf16x8 bih[4][4], bhh[4][2];
    float bias[4];
    #pragma unroll
    for (int j = 0; j < 4; ++j){
      const int col = (wq + 4*j)*16 + lr;
      bias[j] = wb[ld*256 + col];
      const u16* pih = wWihB + (size_t)(ld*256 + col)*128 + lg*8;
      #pragma unroll
      for (int kk = 0; kk < 4; ++kk) bih[j][kk] = *(const bf16x8*)(pih + kk*32);
      const u16* phh = wWhhB + (size_t)(ld*256 + col)*64 + lg*8;
      #pragma unroll
      for (int kk = 0; kk < 2; ++kk) bhh[j][kk] = *(const bf16x8*)(phh + kk*32);
    }
    float cst[4] = {0.f, 0.f, 0.f, 0.f};
    for (int i = tid; i < 2*2*16*64; i += 512) ((u16*)Hb)[i] = 0;
    __syncthreads();
    int cur = 0;
    // layer-0: prefetch first step's X frags from global emb
    bf16x8 xfn[4];
    if (layer == 0){
      const int t0 = dq ? 15 : 0;
      const u16* xp = embB + (size_t)chs[lr*16 + t0]*128 + lg*8;
      #pragma unroll
      for (int kk = 0; kk < 4; ++kk) xfn[kk] = *(const bf16x8*)(xp + kk*32);
    }
    for (int step = 0; step < 16; ++step){
      const int t = dq ? (15 - step) : step;
      f32x4 ac[4];
      #pragma unroll
      for (int j = 0; j < 4; ++j) ac[j] = (f32x4){bias[j], bias[j], bias[j], bias[j]};
      // ih: A = X_t[16 words, 128]
      if (layer == 0){
        bf16x8 xf[4];
        #pragma unroll
        for (int kk = 0; kk < 4; ++kk) xf[kk] = xfn[kk];
        if (step < 15){
          const int tn = dq ? (14 - step) : (step + 1);
          const u16* xp = embB + (size_t)chs[lr*16 + tn]*128 + lg*8;
          #pragma unroll
          for (int kk = 0; kk < 4; ++kk) xfn[kk] = *(const bf16x8*)(xp + kk*32);
        }
        #pragma unroll
        for (int kk = 0; kk < 4; ++kk){
          #pragma unroll
          for (int j = 0; j < 4; ++j)
            ac[j] = __builtin_amdgcn_mfma_f32_16x16x32_bf16(xf[kk], bih[j][kk], ac[j], 0, 0, 0);
        }
      } else {
        #pragma unroll
        for (int kk = 0; kk < 4; ++kk){
          const int c = (kk*4 + lg) ^ lr;
          bf16x8 a = *(const bf16x8*)&SQ[((lr*16 + t)*16 + c)*8];
          #pragma unroll
          for (int j = 0; j < 4; ++j)
            ac[j] = __builtin_amdgcn_mfma_f32_16x16x32_bf16(a, bih[j][kk], ac[j], 0, 0, 0);
        }
      }
      // hh: A = H[16,64]
      #pragma unroll
      for (int kk = 0; kk < 2; ++kk){
        const int c = (kk*4 + lg) ^ (lr & 7);
        bf16x8 a = *(const bf16x8*)&Hb[dq][cur][(lr*8 + c)*8];
        #pragma unroll
        for (int j = 0; j < 4; ++j)
          ac[j] = __builtin_amdgcn_mfma_f32_16x16x32_bf16(a, bhh[j][kk], ac[j], 0, 0, 0);
      }
      const int u = wq*16 + lr;            // unit 0..63 within dir
      #pragma unroll
      for (int r = 0; r < 4; ++r){
        const int w = lg*4 + r;
        float ig = fsigm(ac[0][r]);
        float fg = fsigm(ac[1][r]);
        float gg = ftanh(ac[2][r]);
        float og = fsigm(ac[3][r]);
        cst[r] = fg*cst[r] + ig*gg;
        float hn = og * ftanh(cst[r]);
        u16 hb = f2bu(hn);
        Hb[dq][cur^1][(w*8 + ((u >> 3) ^ (w & 7)))*8 + (u & 7)] = hb;
        const int d = dq*64 + u;
        const int dc = (d >> 3) ^ (w & 15);
        if (layer == 0)       SQ[((w*16 + t)*16 + dc)*8 + (d & 7)] = hb;
        else if (step == 15)  HF[(w*16 + dc)*8 + (d & 7)] = hb;
      }
      __syncthreads();
      cur ^= 1;
    }
  }

  // MLP GEMM1: 8 waves x 1 tile (128 cols); A1 aliases Hb
  {
    const int col = wv*16 + lr;
    float bs = fb1[col];
    bf16x8 b1[4];
    const u16* src = fW1B + (size_t)col*128 + lg*8;
    #pragma unroll
    for (int kk = 0; kk < 4; ++kk) b1[kk] = *(const bf16x8*)(src + kk*32);
    f32x4 ac = (f32x4){bs, bs, bs, bs};
    #pragma unroll
    for (int kk = 0; kk < 4; ++kk){
      const int c = (kk*4 + lg) ^ lr;
      bf16x8 a = *(const bf16x8*)&HF[(lr*16 + c)*8];
      ac = __builtin_amdgcn_mfma_f32_16x16x32_bf16(a, b1[kk], ac, 0, 0, 0);
    }
    __syncthreads();   // Hb no longer read as H; safe to overwrite as A1
    #pragma unroll
    for (int r = 0; r < 4; ++r){
      const int w = lg*4 + r;
      A1[(w*16 + ((col >> 3) ^ (w & 15)))*8 + (col & 7)] = f2bu(fmaxf(ac[r], 0.f));
    }
  }
  __syncthreads();
  // MLP GEMM2 (masked for empty sentence slots)
  {
    const int col = wv*16 + lr;
    float bs = fb2[col];
    bf16x8 b2[4];
    const u16* src = fW2B + (size_t)col*128 + lg*8;
    #pragma unroll
    for (int kk = 0; kk < 4; ++kk) b2[kk] = *(const bf16x8*)(src + kk*32);
    f32x4 ac = (f32x4){bs, bs, bs, bs};
    #pragma unroll
    for (int kk = 0; kk < 4; ++kk){
      const int c = (kk*4 + lg) ^ lr;
      bf16x8 a = *(const bf16x8*)&A1[(lr*16 + c)*8];
      ac = __builtin_amdgcn_mfma_f32_16x16x32_bf16(a, b2[kk], ac, 0, 0, 0);
    }
    u16* wo = (u16*)we_out;
    #pragma unroll
    for (int r = 0; r < 4; ++r){
      const int w = lg*4 + r;
      wo[(size_t)(wbase + w)*128 + col] = emptyf[w] ? (u16)0 : f2bu(ac[r]);
    }
  }
}

// =====================================================================
// Kernel 2 (MFMA GEMM): xw[row][1024] = X[row][K] @ W[1024][K]^T + b.
// =====================================================================
template<int KK>
__global__ __launch_bounds__(256, 1) void xw_gemm(
    const u16* __restrict__ X, const u16* __restrict__ W,
    const float* __restrict__ bias, float* __restrict__ out)
{
  const int rowb = blockIdx.x;
  const int colb = blockIdx.y;
  const int tid = threadIdx.x;
  const int lane = tid & 63, wv = tid >> 6;
  const int lr = lane & 15, lg = lane >> 4;
  const int K = KK*32;

  bf16x8 bf[4][KK];
  f32x4 ac[4];
  #pragma unroll
  for (int j = 0; j < 4; ++j){
    const int g = colb*256 + (wv*4 + j)*16 + lr;
    const float bs = bias[g];
    ac[j] = (f32x4){bs, bs, bs, bs};
    const u16* src = W + (size_t)g*K + lg*8;
    #pragma unroll
    for (int kk = 0; kk < KK; ++kk) bf[j][kk] = *(const bf16x8*)(src + kk*32);
  }
  const u16* xr = X + (size_t)(rowb*16 + lr)*K + lg*8;
  #pragma unroll
  for (int kk = 0; kk < KK; ++kk){
    bf16x8 a = *(const bf16x8*)(xr + kk*32);
    #pragma unroll
    for (int j = 0; j < 4; ++j)
      ac[j] = __builtin_amdgcn_mfma_f32_16x16x32_bf16(a, bf[j][kk], ac[j], 0, 0, 0);
  }
  #pragma unroll
  for (int j = 0; j < 4; ++j){
    const int g = colb*256 + (wv*4 + j)*16 + lr;
    #pragma unroll
    for (int r = 0; r < 4; ++r)
      out[(size_t)(rowb*16 + lg*4 + r)*1024 + g] = ac[j][r];
  }
}

// =====================================================================
// Kernel 3 (MFMA): sentence recurrence (hh only; ih precomputed in xw).
// (round-10 body: depth-1 prefetch, full __syncthreads)
// =====================================================================
__global__ __launch_bounds__(512, 1) void sent_rec(
    const float* __restrict__ xw /* [8192][1024] */,
    const u16* __restrict__ sWhhB /* [4*512][128] */,
    bf16_t* __restrict__ l0out /* layer0: [8192][256] */,
    float* __restrict__ sfin /* layer1: [128][256] */,
    const int layer)
{
  const int dir = blockIdx.x & 1;
  const int sg0 = (blockIdx.x >> 1) << 4;
  const int tid = threadIdx.x;
  const int lane = tid & 63, wv = tid >> 6;
  const int lr = lane & 15, lg = lane >> 4;

  __shared__ __align__(16) u16 Hs[2][2048];

  bf16x8 bhh[4][4];
  #pragma unroll
  for (int j = 0; j < 4; ++j){
    const int g = (wv + 8*j)*16 + lr;
    const u16* p = sWhhB + (size_t)((layer*2 + dir)*512 + g)*128 + lg*8;
    #pragma unroll
    for (int kk = 0; kk < 4; ++kk) bhh[j][kk] = *(const bf16x8*)(p + kk*32);
  }
  for (int i = tid; i < 4096; i += 512) ((u16*)Hs)[i] = 0;
  float cst[4] = {0.f, 0.f, 0.f, 0.f};

  size_t rowoff[4];
  #pragma unroll
  for (int r = 0; r < 4; ++r)
    rowoff[r] = (size_t)(sg0 + lg*4 + r)*64*1024 + dir*512 + wv*16 + lr;

  float xwv[16], xwn[16];
  {
    const int t0 = dir ? 63 : 0;
    #pragma unroll
    for (int j = 0; j < 4; ++j)
      #pragma unroll
      for (int r = 0; r < 4; ++r)
        xwv[j*4 + r] = xw[rowoff[r] + (size_t)t0*1024 + j*128];
  }
  __syncthreads();

  u16* lob = (u16*)l0out;
  int cur = 0;
  for (int step = 0; step < 64; ++step){
    const int t = dir ? (63 - step) : step;
    f32x4 ac[4];
    #pragma unroll
    for (int j = 0; j < 4; ++j)
      ac[j] = (f32x4){xwv[j*4+0], xwv[j*4+1], xwv[j*4+2], xwv[j*4+3]};
    if (step < 63){
      const int tn = dir ? (62 - step) : (step + 1);
      #pragma unroll
      for (int j = 0; j < 4; ++j)
        #pragma unroll
        for (int r = 0; r < 4; ++r)
          xwn[j*4 + r] = xw[rowoff[r] + (size_t)tn*1024 + j*128];
    }
    #pragma unroll
    for (int kk = 0; kk < 4; ++kk){
      const bf16x8 ha = *(const bf16x8*)&Hs[cur][(lr*16 + ((kk*4 + lg) ^ lr))*8];
      #pragma unroll
      for (int j = 0; j < 4; ++j)
        ac[j] = __builtin_amdgcn_mfma_f32_16x16x32_bf16(ha, bhh[j][kk], ac[j], 0, 0, 0);
    }
    const int u = wv*16 + lr;
    #pragma unroll
    for (int r = 0; r < 4; ++r){
      const int s = lg*4 + r;
      float ig = fsigm(ac[0][r]);
      float fg = fsigm(ac[1][r]);
      float gg = ftanh(ac[2][r]);
      float og = fsigm(ac[3][r]);
      cst[r] = fg*cst[r] + ig*gg;
      float hn = og * ftanh(cst[r]);
      Hs[cur^1][(s*16 + ((u >> 3) ^ s))*8 + (u & 7)] = f2bu(hn);
      if (layer == 0)
        lob[((size_t)(sg0 + s)*64 + t)*256 + dir*128 + u] = f2bu(hn);
      else if (step == 63)
        sfin[(size_t)(sg0 + s)*256 + dir*128 + u] = hn;
    }
    __syncthreads();
    cur ^= 1;
    #pragma unroll
    for (int i = 0; i < 16; ++i) xwv[i] = xwn[i];
  }
}

// =====================================================================
// Kernel 4: head (unchanged). Output f32 [128][2].
// =====================================================================
__global__ __launch_bounds__(256) void head_kernel(
    const float* __restrict__ sfin, const bf16_t* __restrict__ wet,
    const float* __restrict__ sW1, const float* __restrict__ sb1,
    const float* __restrict__ sW2, const float* __restrict__ sb2,
    const float* __restrict__ cW0, const float* __restrict__ cb0,
    const float* __restrict__ cW1, const float* __restrict__ cb1,
    const float* __restrict__ cW2, const float* __restrict__ cb2,
    float* __restrict__ out)
{
  const int bs = blockIdx.x, tid = threadIdx.x;
  __shared__ __align__(16) float hin[256];
  __shared__ __align__(16) float a1[256];
  __shared__ __align__(16) float xcat[384];
  __shared__ __align__(16) float b0o[256];
  __shared__ __align__(16) float h1o[128];
  __shared__ float lg[2];

  hin[tid] = sfin[(size_t)bs*256 + tid];
  if (tid < 64){
    const u32* src = (const u32*)(wet + (size_t)bs*128);
    u32 p = src[tid];
    xcat[256 + tid*2]     = blo(p);
    xcat[256 + tid*2 + 1] = bhi(p);
  }
  __syncthreads();
  {
    const float4* wr = (const float4*)(sW1 + (size_t)tid*256);
    float acc = sb1[tid];
    #pragma unroll
    for (int i = 0; i < 64; ++i){
      float4 v = wr[i]; const float* hp = &hin[i*4];
      acc += hp[0]*v.x + hp[1]*v.y + hp[2]*v.z + hp[3]*v.w;
    }
    a1[tid] = fmaxf(acc, 0.0f);
  }
  __syncthreads();
  {
    const float4* wr = (const float4*)(sW2 + (size_t)tid*256);
    float acc = sb2[tid];
    #pragma unroll
    for (int i = 0; i < 64; ++i){
      float4 v = wr[i]; const float* hp = &a1[i*4];
      acc += hp[0]*v.x + hp[1]*v.y + hp[2]*v.z + hp[3]*v.w;
    }
    xcat[tid] = acc;
  }
  __syncthreads();
  {
    const float4* wr = (const float4*)(cW0 + (size_t)tid*384);
    float acc = cb0[tid];
    #pragma unroll
    for (int i = 0; i < 96; ++i){
      float4 v = wr[i]; const float* hp = &xcat[i*4];
      acc += hp[0]*v.x + hp[1]*v.y + hp[2]*v.z + hp[3]*v.w;
    }
    b0o[tid] = fmaxf(acc, 0.0f);
  }
  __syncthreads();
  if (tid < 128){
    const float4* wr = (const float4*)(cW1 + (size_t)tid*256);
    float acc = cb1[tid];
    #pragma unroll
    for (int i = 0; i < 64; ++i){
      float4 v = wr[i]; const float* hp = &b0o[i*4];
      acc += hp[0]*v.x + hp[1]*v.y + hp[2]*v.z + hp[3]*v.w;
    }
    h1o[tid] = fmaxf(acc, 0.0f);
  }
  __syncthreads();
  if (tid < 2){
    const float4* wr = (const float4*)(cW2 + (size_t)tid*128);
    float acc = cb2[tid];
    #pragma unroll
    for (int i = 0; i < 32; ++i){
      float4 v = wr[i]; const float* hp = &h1o[i*4];
      acc += hp[0]*v.x + hp[1]*v.y + hp[2]*v.z + hp[3]*v.w;
    }
    lg[tid] = acc;
  }
  __syncthreads();
  if (tid == 0){
    float m = fmaxf(lg[0], lg[1]);
    float lse = m + logf(expf(lg[0] - m) + expf(lg[1] - m));
    out[bs*2 + 0] = lg[0] - lse;
    out[bs*2 + 1] = lg[1] - lse;
  }
}

extern "C" void kernel_launch(void* const* d_in, const int* in_sizes, int n_in,
                              void* d_out, int out_size, void* d_ws, size_t ws_size,
                              hipStream_t stream) {
  const int*   sentences = (const int*)d_in[0];
  const int*   words     = (const int*)d_in[1];
  const float* emb    = (const float*)d_in[2];
  const float* wWih   = (const float*)d_in[3];
  const float* wWhh   = (const float*)d_in[4];
  const float* wb     = (const float*)d_in[5];
  const float* fW1    = (const float*)d_in[6];
  const float* fb1    = (const float*)d_in[7];
  const float* fW2    = (const float*)d_in[8];
  const float* fb2    = (const float*)d_in[9];
  const float* sWih0  = (const float*)d_in[10];
  const float* sWih1  = (const float*)d_in[11];
  const float* sWhh   = (const float*)d_in[12];
  const float* sb     = (const float*)d_in[13];
  const float* sW1    = (const float*)d_in[14];
  const float* sb1    = (const float*)d_in[15];
  const float* sW2    = (const float*)d_in[16];
  const float* sb2    = (const float*)d_in[17];
  const float* cW0    = (const float*)d_in[18];
  const float* cb0    = (const float*)d_in[19];
  const float* cW1    = (const float*)d_in[20];
  const float* cb1    = (const float*)d_in[21];
  const float* cW2    = (const float*)d_in[22];
  const float* cb2    = (const float*)d_in[23];

  char* W = (char*)d_ws;
  bf16_t* we   = (bf16_t*)(W + WE_OFF);     // [8320][128] bf16
  bf16_t* l0o  = (bf16_t*)(W + L0O_OFF);    // [8192][256] bf16
  float*  sfin = (float*) (W + SFIN_OFF);   // [128][256] f32
  float*  xw   = (float*) (W + XW_OFF);     // [8192][1024] f32 (reused l0/l1)
  u16*    embB = (u16*)   (W + XW_OFF);     // bf16 emb; overwritten after word_mfma
  u16*    wB   = (u16*)   (W + WB_OFF);     // bf16 weights
  bf16_t* wet  = we + (size_t)8192*128;

  prep_weights<<<dim3(440), dim3(256), 0, stream>>>(
      wWih, wWhh, fW1, fW2, sWih0, sWih1, sWhh, emb, wB, embB);
  word_mfma<<<dim3(520), dim3(512), 0, stream>>>(
      sentences, words, embB,
      wB + SEG_WWIH, wB + SEG_WWHH, wb,
      wB + SEG_FW1, fb1, wB + SEG_FW2, fb2, we);
  xw_gemm<4><<<dim3(512, 4), dim3(256), 0, stream>>>(
      (const u16*)we, wB + SEG_SWIH0, sb, xw);
  sent_rec<<<dim3(16), dim3(512), 0, stream>>>(xw, wB + SEG_SWHH, l0o, sfin, 0);
  xw_gemm<8><<<dim3(512, 4), dim3(256), 0, stream>>>(
      (const u16*)l0o, wB + SEG_SWIH1, sb + 1024, xw);
  sent_rec<<<dim3(16), dim3(512), 0, stream>>>(xw, wB + SEG_SWHH, l0o, sfin, 1);
  head_kernel<<<dim3(128), dim3(256), 0, stream>>>(
      sfin, wet, sW1, sb1, sW2, sb2, cW0, cb0, cW1, cb1, cW2, cb2,
      (float*)d_out);
}